// Round 13
// baseline (146.705 us; speedup 1.0000x reference)
//
#include <hip/hip_runtime.h>
#include <hip/hip_bf16.h>

typedef __attribute__((ext_vector_type(4))) float f32x4;
typedef __attribute__((ext_vector_type(8))) short s16x8;
typedef __attribute__((ext_vector_type(2))) unsigned long long u64x2;
typedef unsigned long long u64;

#define NB_ 4
#define N_ 4096
#define FI_ 256
#define FO_ 128
#define NROWS 16384       // NB_ * N_
#define SPLIT 4
#define NSTEPS ((N_ / SPLIT) / 32)   // 32 steps of 32 cols

// pack two f32 -> one u32 of 2 bf16 (RNE), first arg in low half
__device__ __forceinline__ unsigned pkbf(float a, float b) {
    __hip_bfloat162 t = __float22bfloat162_rn(make_float2(a, b));
    unsigned r; __builtin_memcpy(&r, &t, 4); return r;
}

// ---------------- K_adjb: adj (268MB) -> bits (8.4MB), m13-style stream -
// wave = one row; 16 x int4 loads (16 B/lane, 1 KB/instr, contiguous).
// Word layout: word w = q*4+c holds ballot of component c of chunk q,
// i.e. col j = q*256 + l*4 + c  <->  word (j>>8)*4 + (j&3), bit (j&255)>>2.
__global__ __launch_bounds__(256) void k_adjb(
    const int* __restrict__ adj, u64* __restrict__ bits)
{
    const int w = threadIdx.x >> 6, l = threadIdx.x & 63;
    const int row = blockIdx.x * 4 + w;                  // 0..16383
    const int4* ap = (const int4*)(adj + (size_t)row * N_);
    u64 mine = 0;
    #pragma unroll
    for (int q = 0; q < 16; ++q) {
        int4 v = ap[q * 64 + l];                         // 1 KB/instr coalesced
        u64 b0 = __ballot(v.x > 0);
        u64 b1 = __ballot(v.y > 0);
        u64 b2 = __ballot(v.z > 0);
        u64 b3 = __ballot(v.w > 0);
        mine = (l == q * 4 + 0) ? b0 : mine;
        mine = (l == q * 4 + 1) ? b1 : mine;
        mine = (l == q * 4 + 2) ? b2 : mine;
        mine = (l == q * 4 + 3) ? b3 : mine;
    }
    bits[(size_t)row * 64 + l] = mine;                   // 512 B coalesced
}

// ---------------- K0: pack W into bf16 hi/lo ----------------------------
__global__ __launch_bounds__(256) void k0_packw(
    const float* __restrict__ Ww, __hip_bfloat16* __restrict__ whi,
    __hip_bfloat16* __restrict__ wlo)
{
    int idx = blockIdx.x * 256 + threadIdx.x;           // 32768 elems
    float v = Ww[idx];
    __hip_bfloat16 hi = __float2bfloat16(v);
    whi[idx] = hi;
    wlo[idx] = __float2bfloat16(v - __bfloat162float(hi));
}

// ---------------- K1: Wh GEMM + fused epilogue --------------------------
// 1024 blocks x 16 rows(j). Emits WhTf = fragment-major bf16 tiles:
// WhTf[b][jblk][frag o>>4][lane (o&15)+16*(jin>>3)][elem jin&7]
__global__ __launch_bounds__(256) void k1_wh(
    const float* __restrict__ h, const __hip_bfloat16* __restrict__ whi,
    const __hip_bfloat16* __restrict__ wlo, const float* __restrict__ Wb,
    const float* __restrict__ aw, const float* __restrict__ ab,
    short* __restrict__ WhTf, float* __restrict__ srcv,
    float* __restrict__ dstbv, unsigned* __restrict__ auxp)
{
    __shared__ float lds[16][132];
    const int tid = threadIdx.x;
    const int w = tid >> 6, l = tid & 63;
    const int lr = l & 15, g = l >> 4;
    const int r0 = blockIdx.x * 16;
    const float* hp = h + (size_t)(r0 + lr) * FI_ + g * 8;

    f32x4 acc[2] = {(f32x4)0.f, (f32x4)0.f};

    #pragma unroll
    for (int kt = 0; kt < 8; ++kt) {
        f32x4 x0 = *(const f32x4*)(hp + kt * 32);
        f32x4 x1 = *(const f32x4*)(hp + kt * 32 + 4);
        float xx[8];
        #pragma unroll
        for (int t = 0; t < 4; ++t) { xx[t] = x0[t]; xx[t + 4] = x1[t]; }
        union { s16x8 v; unsigned u[4]; } ahi, alo;
        #pragma unroll
        for (int t = 0; t < 4; ++t) {
            float a0 = xx[2 * t], a1 = xx[2 * t + 1];
            unsigned uh = pkbf(a0, a1);
            ahi.u[t] = uh;
            float h0f = __uint_as_float(uh << 16);
            float h1f = __uint_as_float(uh & 0xffff0000u);
            alo.u[t] = pkbf(a0 - h0f, a1 - h1f);
        }
        #pragma unroll
        for (int c = 0; c < 2; ++c) {
            const int o = w * 32 + c * 16 + lr;
            s16x8 bh = *(const s16x8*)(whi + (size_t)o * FI_ + kt * 32 + g * 8);
            s16x8 bl = *(const s16x8*)(wlo + (size_t)o * FI_ + kt * 32 + g * 8);
            acc[c] = __builtin_amdgcn_mfma_f32_16x16x32_bf16(ahi.v, bh, acc[c], 0, 0, 0);
            acc[c] = __builtin_amdgcn_mfma_f32_16x16x32_bf16(alo.v, bh, acc[c], 0, 0, 0);
            acc[c] = __builtin_amdgcn_mfma_f32_16x16x32_bf16(ahi.v, bl, acc[c], 0, 0, 0);
        }
    }

    #pragma unroll
    for (int c = 0; c < 2; ++c) {
        int col = w * 32 + c * 16 + lr;
        float wb = Wb[col];
        #pragma unroll
        for (int kk = 0; kk < 4; ++kk)
            lds[g * 4 + kk][col] = acc[c][kk] + wb;   // local j x o
    }
    __syncthreads();

    {   // WhTf fragment-major store: thread -> (o = t>>1, joct = t&1), 16 B
        const int o = tid >> 1, joct = tid & 1;
        const int jblk = (r0 & 4095) >> 5;
        const int bb = r0 >> 12;
        const int lb = ((r0 >> 3) & 3) + joct;        // jin>>3
        union { s16x8 v; unsigned u[4]; } af;
        #pragma unroll
        for (int q = 0; q < 4; ++q)
            af.u[q] = pkbf(lds[joct * 8 + 2 * q][o], lds[joct * 8 + 2 * q + 1][o]);
        short* dst = WhTf + (((size_t)bb * 128 + jblk) * 8 + (o >> 4)) * 512
                          + ((o & 15) + 16 * lb) * 8;
        *(s16x8*)dst = af.v;
    }

    {   // per-row src/dst dots + exp tables
        const int row = tid >> 4, seg = tid & 15;
        float sp = 0.f, dp = 0.f;
        #pragma unroll
        for (int i = 0; i < 8; ++i) {
            float v = lds[row][seg * 8 + i];
            sp += v * aw[seg * 8 + i];
            dp += v * aw[FO_ + seg * 8 + i];
        }
        #pragma unroll
        for (int off = 8; off >= 1; off >>= 1) {
            sp += __shfl_xor(sp, off);
            dp += __shfl_xor(dp, off);
        }
        if (seg == 0) {
            int r = r0 + row;
            srcv[r] = sp;
            float db = dp + ab[0];
            dstbv[r] = db;
            auxp[r] = pkbf(__expf(db), __expf(0.01f * db));   // lo=e1, hi=e2
        }
    }
}

// ---------------- K2b: per-batch max of dstbv ---------------------------
__global__ __launch_bounds__(256) void k2b_max(
    const float* __restrict__ dstbv, float* __restrict__ maxv)
{
    const int b = blockIdx.x;
    const int t = threadIdx.x, w = t >> 6, l = t & 63;
    float m = -3.4e38f;
    for (int i = t; i < N_; i += 256) m = fmaxf(m, dstbv[b * N_ + i]);
    #pragma unroll
    for (int off = 32; off >= 1; off >>= 1) m = fmaxf(m, __shfl_xor(m, off));
    __shared__ float red[4];
    if (l == 0) red[w] = m;
    __syncthreads();
    if (t == 0) maxv[b] = fmaxf(fmaxf(red[0], red[1]), fmaxf(red[2], red[3]));
}

// ---------------- K3: bits softmax + PV, no LDS / no barriers in loop ---
// grid (256, SPLIT): x = b*64 + rowblk(64 rows). 4 waves:
//   wave w: rh=w&1 -> rows rh*32 + rt*16 (2 rowsets), oh=w>>1 -> 64 o-cols
// Bits: one 32-B word-group per row per 256 cols (8 steps), depth-1
// prefetched. B-frags from L2 (fragment-major WhTf). Waves free-run.
__global__ __launch_bounds__(256, 4) void k3_gat(
    const u64* __restrict__ bits, const short* __restrict__ WhTf,
    const float* __restrict__ srcv, const unsigned* __restrict__ auxp,
    const float* __restrict__ maxv, float* __restrict__ pacc,
    float* __restrict__ prow)
{
    __shared__ float rsum[64];

    const int t = threadIdx.x;
    const int w = t >> 6, l = t & 63;
    const int lr = l & 15, g = l >> 4;
    const int rh = w & 1, oh = w >> 1;
    const int b = blockIdx.x >> 6;
    const int rblk = (blockIdx.x & 63) * 64;
    const int bN = b * N_;
    const int j0 = blockIdx.y * (N_ / SPLIT);

    float C1r[2], C2r[2];
    int row[2];
    {
        const float mdb = maxv[b];
        #pragma unroll
        for (int rt = 0; rt < 2; ++rt) {
            row[rt] = rblk + rh * 32 + rt * 16 + lr;
            float s = srcv[bN + row[rt]];
            float eub = s + mdb;
            float m = fmaxf(eub, 0.01f * eub);           // >= row max of LR(e)
            C1r[rt] = __expf(s - m);
            C2r[rt] = __expf(0.01f * s - m);
        }
    }

    // word offset of col j0 within row: (j0>>8)*4 == j0>>6 (j0 % 256 == 0)
    const u64* bp0 = bits + (size_t)(bN + row[0]) * 64 + (j0 >> 6);
    const u64* bp1 = bits + (size_t)(bN + row[1]) * 64 + (j0 >> 6);
    const unsigned* axp = auxp + (size_t)bN + j0 + g * 8;
    const short* whsrc = WhTf + ((size_t)b * 128 + (j0 >> 5)) * 4096;

    f32x4 acc[2][4];
    #pragma unroll
    for (int rt = 0; rt < 2; ++rt)
        #pragma unroll
        for (int ot = 0; ot < 4; ++ot) acc[rt][ot] = (f32x4)0.f;
    float rs0 = 0.f, rs1 = 0.f;

    // bit word-groups (4 u64 per rowset, cover 256 cols = 8 steps)
    u64 cw0[4], cw1[4], nw0[4], nw1[4];
    {
        u64x2 a0 = *(const u64x2*)(bp0);
        u64x2 a1 = *(const u64x2*)(bp0 + 2);
        u64x2 b0 = *(const u64x2*)(bp1);
        u64x2 b1 = *(const u64x2*)(bp1 + 2);
        cw0[0] = a0[0]; cw0[1] = a0[1]; cw0[2] = a1[0]; cw0[3] = a1[1];
        cw1[0] = b0[0]; cw1[1] = b0[1]; cw1[2] = b1[0]; cw1[3] = b1[1];
        nw0[0] = nw0[1] = nw0[2] = nw0[3] = 0;
        nw1[0] = nw1[1] = nw1[2] = nw1[3] = 0;
    }
    uint4 xc0 = *(const uint4*)(axp);
    uint4 xc1 = *(const uint4*)(axp + 4);

    for (int s = 0; s < NSTEPS; ++s) {
        // B-frag loads for THIS step, issued first (L2 latency < decode time)
        const short* bp = whsrc + (size_t)s * 4096;
        s16x8 Bf[4];
        #pragma unroll
        for (int ot = 0; ot < 4; ++ot)
            Bf[ot] = *(const s16x8*)(bp + (oh * 4 + ot) * 512 + l * 8);

        // prefetch aux (depth-1) and next bit word-group (per 8 steps)
        uint4 xn0 = {0, 0, 0, 0}, xn1 = {0, 0, 0, 0};
        if (s + 1 < NSTEPS) {
            xn0 = *(const uint4*)(axp + (s + 1) * 32);
            xn1 = *(const uint4*)(axp + (s + 1) * 32 + 4);
        }
        if ((s & 7) == 0 && s + 8 < NSTEPS) {
            const int gq = (s >> 3) + 1;
            u64x2 a0 = *(const u64x2*)(bp0 + gq * 4);
            u64x2 a1 = *(const u64x2*)(bp0 + gq * 4 + 2);
            u64x2 b0 = *(const u64x2*)(bp1 + gq * 4);
            u64x2 b1 = *(const u64x2*)(bp1 + gq * 4 + 2);
            nw0[0] = a0[0]; nw0[1] = a0[1]; nw0[2] = a1[0]; nw0[3] = a1[1];
            nw1[0] = b0[0]; nw1[1] = b0[1]; nw1[2] = b1[0]; nw1[3] = b1[1];
        }

        // decode: col = j0 + s*32 + g*8 + e  ->  word e&3, bit sh0 + (e>>2)
        const int sh0 = ((s & 7) << 3) + g * 2;
        const unsigned ax[8] = {xc0.x, xc0.y, xc0.z, xc0.w,
                                xc1.x, xc1.y, xc1.z, xc1.w};
        float p0[8], p1[8];
        #pragma unroll
        for (int e = 0; e < 8; ++e) {
            float e1f = __uint_as_float(ax[e] << 16);
            float e2f = __uint_as_float(ax[e] & 0xffff0000u);
            float v0 = fmaxf(e1f * C1r[0], e2f * C2r[0]);
            float v1 = fmaxf(e1f * C1r[1], e2f * C2r[1]);
            const int sh = sh0 + (e >> 2);
            p0[e] = ((unsigned)(cw0[e & 3] >> sh) & 1u) ? v0 : 0.f;
            p1[e] = ((unsigned)(cw1[e & 3] >> sh) & 1u) ? v1 : 0.f;
            rs0 += p0[e];
            rs1 += p1[e];
        }
        union { s16x8 v; unsigned u[4]; } af0, af1;
        af0.u[0] = pkbf(p0[0], p0[1]); af0.u[1] = pkbf(p0[2], p0[3]);
        af0.u[2] = pkbf(p0[4], p0[5]); af0.u[3] = pkbf(p0[6], p0[7]);
        af1.u[0] = pkbf(p1[0], p1[1]); af1.u[1] = pkbf(p1[2], p1[3]);
        af1.u[2] = pkbf(p1[4], p1[5]); af1.u[3] = pkbf(p1[6], p1[7]);

        #pragma unroll
        for (int ot = 0; ot < 4; ++ot) {
            acc[0][ot] = __builtin_amdgcn_mfma_f32_16x16x32_bf16(af0.v, Bf[ot], acc[0][ot], 0, 0, 0);
            acc[1][ot] = __builtin_amdgcn_mfma_f32_16x16x32_bf16(af1.v, Bf[ot], acc[1][ot], 0, 0, 0);
        }

        xc0 = xn0; xc1 = xn1;
        if ((s & 7) == 7) {
            #pragma unroll
            for (int q = 0; q < 4; ++q) { cw0[q] = nw0[q]; cw1[q] = nw1[q]; }
        }
    }

    // row-sums: reduce over g-groups, park in LDS for C-layout epilogue
    rs0 += __shfl_xor(rs0, 16); rs0 += __shfl_xor(rs0, 32);
    rs1 += __shfl_xor(rs1, 16); rs1 += __shfl_xor(rs1, 32);
    if (oh == 0 && g == 0) {
        rsum[rh * 32 + lr] = rs0;
        rsum[rh * 32 + 16 + lr] = rs1;
    }
    __syncthreads();

    const size_t sb = (size_t)blockIdx.y * ((size_t)NROWS * FO_);
    #pragma unroll
    for (int rt = 0; rt < 2; ++rt) {
        #pragma unroll
        for (int kk = 0; kk < 4; ++kk) {
            int rloc = rh * 32 + rt * 16 + g * 4 + kk;
            int grow = bN + rblk + rloc;
            float* pp = pacc + sb + (size_t)grow * FO_ + oh * 64 + lr;
            #pragma unroll
            for (int ot = 0; ot < 4; ++ot)
                pp[ot * 16] = acc[rt][ot][kk];
            if (oh == 0 && lr == 0)
                prow[blockIdx.y * NROWS + grow] = rsum[rloc];
        }
    }
}

// ---------------- K4: combine split partials + normalize ----------------
__global__ __launch_bounds__(256) void k4_comb(
    const float* __restrict__ pacc, const float* __restrict__ prow,
    float* __restrict__ out)
{
    const int idx = blockIdx.x * 256 + threadIdx.x;      // 2,097,152
    const int grow = idx >> 7;
    float s = 0.f, rs = 0.f;
    #pragma unroll
    for (int si = 0; si < SPLIT; ++si) {
        s  += pacc[(size_t)si * ((size_t)NROWS * FO_) + idx];
        rs += prow[si * NROWS + grow];
    }
    out[idx] = s / rs;
}

extern "C" void kernel_launch(void* const* d_in, const int* in_sizes, int n_in,
                              void* d_out, int out_size, void* d_ws, size_t ws_size,
                              hipStream_t stream)
{
    const float* h  = (const float*)d_in[0];
    const int* adj  = (const int*)d_in[1];
    const float* Ww = (const float*)d_in[2];
    const float* Wb = (const float*)d_in[3];
    const float* aw = (const float*)d_in[4];
    const float* ab = (const float*)d_in[5];
    float* out = (float*)d_out;

    char* wsb = (char*)d_ws;                             // ws_size ~1 GB
    float* pacc          = (float*)wsb;                               // 32 MB
    short* WhTf          = (short*)(wsb + 33554432u);                 // 4 MB
    u64* bits            = (u64*)(wsb + 37748736u);                   // 8.4 MB
    char* aux            = wsb + 46137344u;
    float* srcv          = (float*)(aux);                             // 64 KB
    float* dstbv         = (float*)(aux + (64u << 10));               // 64 KB
    unsigned* auxp       = (unsigned*)(aux + (128u << 10));           // 64 KB
    __hip_bfloat16* whi  = (__hip_bfloat16*)(aux + (192u << 10));     // 64 KB
    __hip_bfloat16* wlo  = (__hip_bfloat16*)(aux + (256u << 10));     // 64 KB
    float* maxv          = (float*)(aux + (320u << 10));              // 16 B
    float* prow          = (float*)(aux + (384u << 10));              // 256 KB

    k_adjb<<<4096, 256, 0, stream>>>(adj, bits);
    k0_packw<<<128, 256, 0, stream>>>(Ww, whi, wlo);
    k1_wh<<<1024, 256, 0, stream>>>(h, whi, wlo, Wb, aw, ab, WhTf, srcv, dstbv, auxp);
    k2b_max<<<4, 256, 0, stream>>>(dstbv, maxv);
    dim3 g3(NB_ * 64, SPLIT);
    k3_gat<<<g3, 256, 0, stream>>>(bits, WhTf, srcv, auxp, maxv, pacc, prow);
    k4_comb<<<8192, 256, 0, stream>>>(pacc, prow, out);
}

// Round 14
// 146.674 us; speedup vs baseline: 1.0002x; 1.0002x over previous
//
#include <hip/hip_runtime.h>
#include <hip/hip_bf16.h>

typedef __attribute__((ext_vector_type(4))) float f32x4;
typedef __attribute__((ext_vector_type(8))) short s16x8;
typedef unsigned long long u64;

#define NB_ 4
#define N_ 4096
#define FI_ 256
#define FO_ 128
#define NROWS 16384       // NB_ * N_
#define SPLIT 4
#define NSTEPS ((N_ / SPLIT) / 32)   // 32 steps of 32 cols

// pack two f32 -> one u32 of 2 bf16 (RNE), first arg in low half
__device__ __forceinline__ unsigned pkbf(float a, float b) {
    __hip_bfloat162 t = __float22bfloat162_rn(make_float2(a, b));
    unsigned r; __builtin_memcpy(&r, &t, 4); return r;
}

typedef __attribute__((address_space(1))) const void CGV;
typedef __attribute__((address_space(3))) void LDSV;
__device__ __forceinline__ void gload16(const void* g, void* l) {
    __builtin_amdgcn_global_load_lds((CGV*)g, (LDSV*)l, 16, 0, 0);
}

__device__ __forceinline__ unsigned encf(float x) {
    unsigned u = __float_as_uint(x);
    return (u & 0x80000000u) ? ~u : (u | 0x80000000u);
}
__device__ __forceinline__ float decf(unsigned v) {
    unsigned u = (v & 0x80000000u) ? (v ^ 0x80000000u) : ~v;
    return __uint_as_float(u);
}

// ---------------- K0: pack W into bf16 hi/lo ----------------------------
__global__ __launch_bounds__(256) void k0_packw(
    const float* __restrict__ Ww, __hip_bfloat16* __restrict__ whi,
    __hip_bfloat16* __restrict__ wlo)
{
    int idx = blockIdx.x * 256 + threadIdx.x;           // 32768 elems
    float v = Ww[idx];
    __hip_bfloat16 hi = __float2bfloat16(v);
    whi[idx] = hi;
    wlo[idx] = __float2bfloat16(v - __bfloat162float(hi));
}

// ---------------- K1: Wh GEMM + fused epilogue (incl. per-batch max) ----
// 1024 blocks x 16 rows(j). Emits WhTf fragment-major, srcv, auxp, maxenc.
__global__ __launch_bounds__(256) void k1_wh(
    const float* __restrict__ h, const __hip_bfloat16* __restrict__ whi,
    const __hip_bfloat16* __restrict__ wlo, const float* __restrict__ Wb,
    const float* __restrict__ aw, const float* __restrict__ ab,
    short* __restrict__ WhTf, float* __restrict__ srcv,
    unsigned* __restrict__ auxp, unsigned* __restrict__ maxenc)
{
    __shared__ float lds[16][132];
    __shared__ float dbsh[16];
    const int tid = threadIdx.x;
    const int w = tid >> 6, l = tid & 63;
    const int lr = l & 15, g = l >> 4;
    const int r0 = blockIdx.x * 16;
    const float* hp = h + (size_t)(r0 + lr) * FI_ + g * 8;

    f32x4 acc[2] = {(f32x4)0.f, (f32x4)0.f};

    #pragma unroll
    for (int kt = 0; kt < 8; ++kt) {
        f32x4 x0 = *(const f32x4*)(hp + kt * 32);
        f32x4 x1 = *(const f32x4*)(hp + kt * 32 + 4);
        float xx[8];
        #pragma unroll
        for (int t = 0; t < 4; ++t) { xx[t] = x0[t]; xx[t + 4] = x1[t]; }
        union { s16x8 v; unsigned u[4]; } ahi, alo;
        #pragma unroll
        for (int t = 0; t < 4; ++t) {
            float a0 = xx[2 * t], a1 = xx[2 * t + 1];
            unsigned uh = pkbf(a0, a1);
            ahi.u[t] = uh;
            float h0f = __uint_as_float(uh << 16);
            float h1f = __uint_as_float(uh & 0xffff0000u);
            alo.u[t] = pkbf(a0 - h0f, a1 - h1f);
        }
        #pragma unroll
        for (int c = 0; c < 2; ++c) {
            const int o = w * 32 + c * 16 + lr;
            s16x8 bh = *(const s16x8*)(whi + (size_t)o * FI_ + kt * 32 + g * 8);
            s16x8 bl = *(const s16x8*)(wlo + (size_t)o * FI_ + kt * 32 + g * 8);
            acc[c] = __builtin_amdgcn_mfma_f32_16x16x32_bf16(ahi.v, bh, acc[c], 0, 0, 0);
            acc[c] = __builtin_amdgcn_mfma_f32_16x16x32_bf16(alo.v, bh, acc[c], 0, 0, 0);
            acc[c] = __builtin_amdgcn_mfma_f32_16x16x32_bf16(ahi.v, bl, acc[c], 0, 0, 0);
        }
    }

    #pragma unroll
    for (int c = 0; c < 2; ++c) {
        int col = w * 32 + c * 16 + lr;
        float wb = Wb[col];
        #pragma unroll
        for (int kk = 0; kk < 4; ++kk)
            lds[g * 4 + kk][col] = acc[c][kk] + wb;   // local j x o
    }
    __syncthreads();

    {   // WhTf fragment-major store
        const int o = tid >> 1, joct = tid & 1;
        const int jblk = (r0 & 4095) >> 5;
        const int bb = r0 >> 12;
        const int lb = ((r0 >> 3) & 3) + joct;        // jin>>3
        union { s16x8 v; unsigned u[4]; } af;
        #pragma unroll
        for (int q = 0; q < 4; ++q)
            af.u[q] = pkbf(lds[joct * 8 + 2 * q][o], lds[joct * 8 + 2 * q + 1][o]);
        short* dst = WhTf + (((size_t)bb * 128 + jblk) * 8 + (o >> 4)) * 512
                          + ((o & 15) + 16 * lb) * 8;
        *(s16x8*)dst = af.v;
    }

    {   // per-row src/dst dots + exp tables + block max -> atomic
        const int row = tid >> 4, seg = tid & 15;
        float sp = 0.f, dp = 0.f;
        #pragma unroll
        for (int i = 0; i < 8; ++i) {
            float v = lds[row][seg * 8 + i];
            sp += v * aw[seg * 8 + i];
            dp += v * aw[FO_ + seg * 8 + i];
        }
        #pragma unroll
        for (int off = 8; off >= 1; off >>= 1) {
            sp += __shfl_xor(sp, off);
            dp += __shfl_xor(dp, off);
        }
        if (seg == 0) {
            int r = r0 + row;
            srcv[r] = sp;
            float db = dp + ab[0];
            dbsh[row] = db;
            auxp[r] = pkbf(__expf(db), __expf(0.01f * db));   // lo=e1, hi=e2
        }
        __syncthreads();
        if (tid == 0) {
            float m = dbsh[0];
            #pragma unroll
            for (int i = 1; i < 16; ++i) m = fmaxf(m, dbsh[i]);
            atomicMax(&maxenc[r0 >> 12], encf(m));
        }
    }
}

// ---------------- K3: fully-counted LDS pipeline, no reg-carried globals -
// grid (512, SPLIT): x = b*128 + rowblk(32 rows). 4 waves:
//   wave w: rh=w&1 (16 rows), oh=w>>1 (64 o-cols)
// Per step per wave: 1 adj DMA (3-ring, 2-phase flight), 2 wh DMA (2-ring),
// 1 aux DMA (2-ring). Top-of-step s_waitcnt vmcnt(1) + raw barrier.
__global__ __launch_bounds__(256, 4) void k3_gat(
    const int* __restrict__ adj, const short* __restrict__ WhTf,
    const float* __restrict__ srcv, const unsigned* __restrict__ auxp,
    const unsigned* __restrict__ maxenc, float* __restrict__ pacc,
    float* __restrict__ prow)
{
    __shared__ int adjb[3][32][32];            // 12 KB, 16B-chunk XOR swizzle
    __shared__ __hip_bfloat16 whb[2][4096];    // 16 KB, fragment-major
    __shared__ unsigned auxb[2][32];           // 256 B

    const int t = threadIdx.x;
    const int w = t >> 6, l = t & 63;
    const int lr = l & 15, g = l >> 4;
    const int rh = w & 1, oh = w >> 1;
    const int b = blockIdx.x >> 7;
    const int rblk = (blockIdx.x & 127) * 32;
    const int bN = b * N_;
    const int j0 = blockIdx.y * (N_ / SPLIT);

    float C1, C2;
    {
        int r = rblk + rh * 16 + lr;
        float s = srcv[bN + r];
        float eub = s + decf(maxenc[b]);
        float m = fmaxf(eub, 0.01f * eub);                // >= row max of LR(e)
        C1 = __expf(s - m);
        C2 = __expf(0.01f * s - m);
    }

    const unsigned* axsrc = auxp + (size_t)bN + j0;
    const short* whsrc = WhTf + ((size_t)b * 128 + (j0 >> 5)) * 4096;

    f32x4 acc[4];
    #pragma unroll
    for (int ot = 0; ot < 4; ++ot) acc[ot] = (f32x4)0.f;
    float rs = 0.f;

    // adj stage: 256 slots of 16B, 1/thread; LDS chunk c holds src c^(r&7)
    auto stage_adj = [&](int bi, int s) {
        const int jb = j0 + s * 32;
        const int r = t >> 3, c = t & 7;
        gload16(adj + (size_t)(bN + rblk + r) * N_ + jb + ((c ^ (r & 7)) << 2),
                &adjb[bi][0][0] + w * 256);
    };
    // wh stage: 512 slots of 16B, 2/thread, fully contiguous
    auto stage_wh = [&](int bi, int s) {
        const short* src = whsrc + (size_t)s * 4096;
        #pragma unroll
        for (int i = 0; i < 2; ++i)
            gload16(src + (size_t)(i * 256 + t) * 8,
                    &whb[bi][0] + (size_t)(i * 256 + w * 64) * 8);
    };
    // aux stage: 8 slots of 16B; each wave stages its 2 (lanes 0,1)
    auto stage_aux = [&](int bi, int s) {
        if (l < 2)
            gload16(axsrc + s * 32 + (w * 2 + l) * 4, &auxb[bi][w * 8]);
    };

    // prologue: adj(0), aux(0), wh(0), adj(1)  (order = vmcnt count basis)
    stage_adj(0, 0);
    __builtin_amdgcn_sched_barrier(0);
    stage_aux(0, 0);
    stage_wh(0, 0);
    __builtin_amdgcn_sched_barrier(0);
    stage_adj(1, 1);
    __builtin_amdgcn_sched_barrier(0);

    for (int s = 0; s < NSTEPS; ++s) {
        __builtin_amdgcn_sched_barrier(0);
        if (s + 1 < NSTEPS) asm volatile("s_waitcnt vmcnt(1)" ::: "memory");
        else                asm volatile("s_waitcnt vmcnt(0)" ::: "memory");
        __builtin_amdgcn_sched_barrier(0);
        __builtin_amdgcn_s_barrier();
        __builtin_amdgcn_sched_barrier(0);

        const int cur = s & 1, curA = s % 3;
        if (s + 1 < NSTEPS) {
            stage_aux(cur ^ 1, s + 1);
            stage_wh(cur ^ 1, s + 1);
        }
        if (s + 2 < NSTEPS) stage_adj((s + 2) % 3, s + 2);
        __builtin_amdgcn_sched_barrier(0);

        // ---- compute(s): everything from LDS ----
        uint4 x0 = *(const uint4*)&auxb[cur][g * 8];
        uint4 x1 = *(const uint4*)&auxb[cur][g * 8 + 4];
        const int R = rh * 16 + lr;
        const int4 a0 = *(const int4*)&adjb[curA][R][((2 * g) ^ (R & 7)) << 2];
        const int4 a1 = *(const int4*)&adjb[curA][R][(((2 * g) + 1) ^ (R & 7)) << 2];
        s16x8 Bf[4];
        #pragma unroll
        for (int ot = 0; ot < 4; ++ot)
            Bf[ot] = *(const s16x8*)&whb[cur][(size_t)((oh * 4 + ot) * 64 + l) * 8];

        const unsigned ax[8] = {x0.x, x0.y, x0.z, x0.w, x1.x, x1.y, x1.z, x1.w};
        const int av[8] = {a0.x, a0.y, a0.z, a0.w, a1.x, a1.y, a1.z, a1.w};
        float p[8];
        #pragma unroll
        for (int e = 0; e < 8; ++e) {
            float e1f = __uint_as_float(ax[e] << 16);
            float e2f = __uint_as_float(ax[e] & 0xffff0000u);
            float v = fmaxf(e1f * C1, e2f * C2);          // exact LR softmax p
            p[e] = (av[e] > 0) ? v : 0.f;
            rs += p[e];
        }
        union { s16x8 v; unsigned u[4]; } af;
        af.u[0] = pkbf(p[0], p[1]); af.u[1] = pkbf(p[2], p[3]);
        af.u[2] = pkbf(p[4], p[5]); af.u[3] = pkbf(p[6], p[7]);

        #pragma unroll
        for (int ot = 0; ot < 4; ++ot)
            acc[ot] = __builtin_amdgcn_mfma_f32_16x16x32_bf16(
                af.v, Bf[ot], acc[ot], 0, 0, 0);
    }

    // row-sum: combine the 4 lanes sharing lr; write prow lane-direct
    rs += __shfl_xor(rs, 16);
    rs += __shfl_xor(rs, 32);
    if (oh == 0 && g == 0)
        prow[blockIdx.y * NROWS + bN + rblk + rh * 16 + lr] = rs;

    const size_t sb = (size_t)blockIdx.y * ((size_t)NROWS * FO_);
    #pragma unroll
    for (int kk = 0; kk < 4; ++kk) {
        int rloc = rh * 16 + g * 4 + kk;
        int grow = bN + rblk + rloc;
        float* pp = pacc + sb + (size_t)grow * FO_ + oh * 64 + lr;
        #pragma unroll
        for (int ot = 0; ot < 4; ++ot)
            pp[ot * 16] = acc[ot][kk];
    }
}

// ---------------- K4: combine split partials + normalize ----------------
__global__ __launch_bounds__(256) void k4_comb(
    const float* __restrict__ pacc, const float* __restrict__ prow,
    float* __restrict__ out)
{
    const int idx = blockIdx.x * 256 + threadIdx.x;      // 2,097,152
    const int grow = idx >> 7;
    float s = 0.f, rs = 0.f;
    #pragma unroll
    for (int si = 0; si < SPLIT; ++si) {
        s  += pacc[(size_t)si * ((size_t)NROWS * FO_) + idx];
        rs += prow[si * NROWS + grow];
    }
    out[idx] = s / rs;
}

extern "C" void kernel_launch(void* const* d_in, const int* in_sizes, int n_in,
                              void* d_out, int out_size, void* d_ws, size_t ws_size,
                              hipStream_t stream)
{
    const float* h  = (const float*)d_in[0];
    const int* adj  = (const int*)d_in[1];
    const float* Ww = (const float*)d_in[2];
    const float* Wb = (const float*)d_in[3];
    const float* aw = (const float*)d_in[4];
    const float* ab = (const float*)d_in[5];
    float* out = (float*)d_out;

    char* wsb = (char*)d_ws;                             // ws_size ~1 GB
    float* pacc          = (float*)wsb;                               // 32 MB
    short* WhTf          = (short*)(wsb + 33554432u);                 // 4 MB
    char* aux            = wsb + 37748736u;
    float* srcv          = (float*)(aux);                             // 64 KB
    unsigned* auxp       = (unsigned*)(aux + (64u << 10));            // 64 KB
    __hip_bfloat16* whi  = (__hip_bfloat16*)(aux + (128u << 10));     // 64 KB
    __hip_bfloat16* wlo  = (__hip_bfloat16*)(aux + (192u << 10));     // 64 KB
    unsigned* maxenc     = (unsigned*)(aux + (256u << 10));           // 16 B
    float* prow          = (float*)(aux + (320u << 10));              // 256 KB

    hipMemsetAsync(maxenc, 0, NB_ * sizeof(unsigned), stream);
    k0_packw<<<128, 256, 0, stream>>>(Ww, whi, wlo);
    k1_wh<<<1024, 256, 0, stream>>>(h, whi, wlo, Wb, aw, ab, WhTf, srcv, auxp, maxenc);
    dim3 g3(NB_ * 128, SPLIT);
    k3_gat<<<g3, 256, 0, stream>>>(adj, WhTf, srcv, auxp, maxenc, pacc, prow);
    k4_comb<<<8192, 256, 0, stream>>>(pacc, prow, out);
}

// Round 15
// 132.096 us; speedup vs baseline: 1.1106x; 1.1104x over previous
//
#include <hip/hip_runtime.h>
#include <hip/hip_bf16.h>

typedef __attribute__((ext_vector_type(4))) float f32x4;
typedef __attribute__((ext_vector_type(8))) short s16x8;
typedef unsigned long long u64;

#define NB_ 4
#define N_ 4096
#define FI_ 256
#define FO_ 128
#define NROWS 16384       // NB_ * N_
#define SPLIT 4
#define NSTEPS ((N_ / SPLIT) / 32)   // 32 steps of 32 cols

// pack two f32 -> one u32 of 2 bf16 (RNE), first arg in low half
__device__ __forceinline__ unsigned pkbf(float a, float b) {
    __hip_bfloat162 t = __float22bfloat162_rn(make_float2(a, b));
    unsigned r; __builtin_memcpy(&r, &t, 4); return r;
}

typedef __attribute__((address_space(1))) const void CGV;
typedef __attribute__((address_space(3))) void LDSV;
__device__ __forceinline__ void gload16(const void* g, void* l) {
    __builtin_amdgcn_global_load_lds((CGV*)g, (LDSV*)l, 16, 0, 0);
}

__device__ __forceinline__ unsigned encf(float x) {
    unsigned u = __float_as_uint(x);
    return (u & 0x80000000u) ? ~u : (u | 0x80000000u);
}
__device__ __forceinline__ float decf(unsigned v) {
    unsigned u = (v & 0x80000000u) ? (v ^ 0x80000000u) : ~v;
    return __uint_as_float(u);
}

// ---------------- K0: pack W into bf16 hi/lo; zero maxenc ---------------
__global__ __launch_bounds__(256) void k0_packw(
    const float* __restrict__ Ww, __hip_bfloat16* __restrict__ whi,
    __hip_bfloat16* __restrict__ wlo, unsigned* __restrict__ maxenc)
{
    int idx = blockIdx.x * 256 + threadIdx.x;           // 32768 elems
    if (blockIdx.x == 0 && threadIdx.x < NB_) maxenc[threadIdx.x] = 0u;
    float v = Ww[idx];
    __hip_bfloat16 hi = __float2bfloat16(v);
    whi[idx] = hi;
    wlo[idx] = __float2bfloat16(v - __bfloat162float(hi));
}

// ---------------- K1: Wh GEMM + fused epilogue (+ per-batch max) --------
// 1024 blocks x 16 rows(j). Emits WhTf = fragment-major bf16 tiles:
// WhTf[b][jblk][frag o>>4][lane (o&15)+16*(jin>>3)][elem jin&7]
__global__ __launch_bounds__(256) void k1_wh(
    const float* __restrict__ h, const __hip_bfloat16* __restrict__ whi,
    const __hip_bfloat16* __restrict__ wlo, const float* __restrict__ Wb,
    const float* __restrict__ aw, const float* __restrict__ ab,
    short* __restrict__ WhTf, float* __restrict__ srcv,
    unsigned* __restrict__ auxp, unsigned* __restrict__ maxenc)
{
    __shared__ float lds[16][132];
    __shared__ float dbsh[16];
    const int tid = threadIdx.x;
    const int w = tid >> 6, l = tid & 63;
    const int lr = l & 15, g = l >> 4;
    const int r0 = blockIdx.x * 16;
    const float* hp = h + (size_t)(r0 + lr) * FI_ + g * 8;

    f32x4 acc[2] = {(f32x4)0.f, (f32x4)0.f};

    #pragma unroll
    for (int kt = 0; kt < 8; ++kt) {
        f32x4 x0 = *(const f32x4*)(hp + kt * 32);
        f32x4 x1 = *(const f32x4*)(hp + kt * 32 + 4);
        float xx[8];
        #pragma unroll
        for (int t = 0; t < 4; ++t) { xx[t] = x0[t]; xx[t + 4] = x1[t]; }
        union { s16x8 v; unsigned u[4]; } ahi, alo;
        #pragma unroll
        for (int t = 0; t < 4; ++t) {
            float a0 = xx[2 * t], a1 = xx[2 * t + 1];
            unsigned uh = pkbf(a0, a1);
            ahi.u[t] = uh;
            float h0f = __uint_as_float(uh << 16);
            float h1f = __uint_as_float(uh & 0xffff0000u);
            alo.u[t] = pkbf(a0 - h0f, a1 - h1f);
        }
        #pragma unroll
        for (int c = 0; c < 2; ++c) {
            const int o = w * 32 + c * 16 + lr;
            s16x8 bh = *(const s16x8*)(whi + (size_t)o * FI_ + kt * 32 + g * 8);
            s16x8 bl = *(const s16x8*)(wlo + (size_t)o * FI_ + kt * 32 + g * 8);
            acc[c] = __builtin_amdgcn_mfma_f32_16x16x32_bf16(ahi.v, bh, acc[c], 0, 0, 0);
            acc[c] = __builtin_amdgcn_mfma_f32_16x16x32_bf16(alo.v, bh, acc[c], 0, 0, 0);
            acc[c] = __builtin_amdgcn_mfma_f32_16x16x32_bf16(ahi.v, bl, acc[c], 0, 0, 0);
        }
    }

    #pragma unroll
    for (int c = 0; c < 2; ++c) {
        int col = w * 32 + c * 16 + lr;
        float wb = Wb[col];
        #pragma unroll
        for (int kk = 0; kk < 4; ++kk)
            lds[g * 4 + kk][col] = acc[c][kk] + wb;   // local j x o
    }
    __syncthreads();

    {   // WhTf fragment-major store: thread -> (o = t>>1, joct = t&1), 16 B
        const int o = tid >> 1, joct = tid & 1;
        const int jblk = (r0 & 4095) >> 5;
        const int bb = r0 >> 12;
        const int lb = ((r0 >> 3) & 3) + joct;        // jin>>3
        union { s16x8 v; unsigned u[4]; } af;
        #pragma unroll
        for (int q = 0; q < 4; ++q)
            af.u[q] = pkbf(lds[joct * 8 + 2 * q][o], lds[joct * 8 + 2 * q + 1][o]);
        short* dst = WhTf + (((size_t)bb * 128 + jblk) * 8 + (o >> 4)) * 512
                          + ((o & 15) + 16 * lb) * 8;
        *(s16x8*)dst = af.v;
    }

    {   // per-row src/dst dots + exp tables + block max -> atomic
        const int row = tid >> 4, seg = tid & 15;
        float sp = 0.f, dp = 0.f;
        #pragma unroll
        for (int i = 0; i < 8; ++i) {
            float v = lds[row][seg * 8 + i];
            sp += v * aw[seg * 8 + i];
            dp += v * aw[FO_ + seg * 8 + i];
        }
        #pragma unroll
        for (int off = 8; off >= 1; off >>= 1) {
            sp += __shfl_xor(sp, off);
            dp += __shfl_xor(dp, off);
        }
        if (seg == 0) {
            int r = r0 + row;
            srcv[r] = sp;
            float db = dp + ab[0];
            dbsh[row] = db;
            auxp[r] = pkbf(__expf(db), __expf(0.01f * db));   // lo=e1, hi=e2
        }
        __syncthreads();
        if (tid == 0) {
            float m = dbsh[0];
            #pragma unroll
            for (int i = 1; i < 16; ++i) m = fmaxf(m, dbsh[i]);
            atomicMax(&maxenc[r0 >> 12], encf(m));
        }
    }
}

// ---------------- K3: wave-contiguous adj/WhTf staging + softmax + PV ---
// (R9 champion structure, verbatim) grid (256, SPLIT): x = b*64 + rowblk.
// 4 waves: rh=w&1 (rows rh*32 + rt*16), oh=w>>1 (o-half, 64 cols)
__global__ __launch_bounds__(256, 4) void k3_gat(
    const int* __restrict__ adj, const short* __restrict__ WhTf,
    const float* __restrict__ srcv, const unsigned* __restrict__ auxp,
    const unsigned* __restrict__ maxenc, float* __restrict__ pacc,
    float* __restrict__ prow)
{
    __shared__ int adjb[2][64][32];            // 2 x 8 KB, 16B-chunk swizzled
    __shared__ __hip_bfloat16 whb[2][4096];    // 2 x 8 KB, fragment-major
    __shared__ float rsum[64];

    const int t = threadIdx.x;
    const int w = t >> 6, l = t & 63;
    const int lr = l & 15, g = l >> 4;
    const int rh = w & 1, oh = w >> 1;
    const int b = blockIdx.x >> 6;
    const int rblk = (blockIdx.x & 63) * 64;              // block row base
    const int bN = b * N_;
    const int j0 = blockIdx.y * (N_ / SPLIT);

    float C1[2], C2[2];
    {
        const float mdb = decf(maxenc[b]);
        #pragma unroll
        for (int rt = 0; rt < 2; ++rt) {
            int r = rblk + rh * 32 + rt * 16 + lr;
            float s = srcv[bN + r];
            float eub = s + mdb;
            float m = fmaxf(eub, 0.01f * eub);            // >= row max of LR(e)
            C1[rt] = __expf(s - m);
            C2[rt] = __expf(0.01f * s - m);
        }
    }

    const unsigned* axp = auxp + (size_t)bN + j0 + g * 8;
    const short* whsrc = WhTf + ((size_t)b * 128 + (j0 >> 5)) * 4096;

    f32x4 acc[2][4];
    #pragma unroll
    for (int rt = 0; rt < 2; ++rt)
        #pragma unroll
        for (int ot = 0; ot < 4; ++ot) acc[rt][ot] = (f32x4)0.f;
    float rs0 = 0.f, rs1 = 0.f;

    // adj stage: slot = r*8+c; LDS chunk c holds source chunk c^(r&7)
    auto stage_adj = [&](int bi, int s) {
        const int jb = j0 + s * 32;
        #pragma unroll
        for (int i = 0; i < 2; ++i) {
            int r = (t >> 3) + i * 32;                    // 0..63
            int c = t & 7;
            const int* src = adj + (size_t)(bN + rblk + r) * N_ + jb
                                 + ((c ^ (r & 7)) << 2);
            gload16(src, &adjb[bi][0][0] + (size_t)(i * 256 + w * 64) * 4);
        }
    };
    // WhTf stage: fully contiguous 8 KB
    auto stage_wh = [&](int bi, int s) {
        const short* src = whsrc + (size_t)s * 4096;
        #pragma unroll
        for (int i = 0; i < 2; ++i)
            gload16(src + (size_t)(i * 256 + t) * 8,
                    &whb[bi][0] + (size_t)(i * 256 + w * 64) * 8);
    };

    uint4 xc0, xc1;
    stage_adj(0, 0);
    stage_wh(0, 0);
    xc0 = *(const uint4*)(axp);
    xc1 = *(const uint4*)(axp + 4);
    __syncthreads();
    int cur = 0;

    for (int s = 0; s < NSTEPS; ++s) {
        uint4 xn0 = {0, 0, 0, 0}, xn1 = {0, 0, 0, 0};
        const bool more = (s + 1 < NSTEPS);
        if (more) {
            stage_adj(cur ^ 1, s + 1);
            stage_wh(cur ^ 1, s + 1);
            const int jn = (s + 1) * 32;
            xn0 = *(const uint4*)(axp + jn);
            xn1 = *(const uint4*)(axp + jn + 4);
        }

        // shared unpack of e1/e2 (same j for both rowsets)
        const unsigned ax[8] = {xc0.x, xc0.y, xc0.z, xc0.w,
                                xc1.x, xc1.y, xc1.z, xc1.w};
        float e1f[8], e2f[8];
        #pragma unroll
        for (int e = 0; e < 8; ++e) {
            e1f[e] = __uint_as_float(ax[e] << 16);
            e2f[e] = __uint_as_float(ax[e] & 0xffff0000u);
        }
        // B fragments (shared by both rowsets)
        s16x8 Bf[4];
        #pragma unroll
        for (int ot = 0; ot < 4; ++ot)
            Bf[ot] = *(const s16x8*)&whb[cur][(size_t)((oh * 4 + ot) * 64 + l) * 8];

        #pragma unroll
        for (int rt = 0; rt < 2; ++rt) {
            const int R = rh * 32 + rt * 16 + lr;
            const int4 a0 = *(const int4*)&adjb[cur][R][((2 * g) ^ (R & 7)) << 2];
            const int4 a1 = *(const int4*)&adjb[cur][R][((2 * g + 1) ^ (R & 7)) << 2];
            const int av[8] = {a0.x, a0.y, a0.z, a0.w, a1.x, a1.y, a1.z, a1.w};
            float p[8];
            #pragma unroll
            for (int e = 0; e < 8; ++e) {
                float v = fmaxf(e1f[e] * C1[rt], e2f[e] * C2[rt]);
                p[e] = (av[e] > 0) ? v : 0.f;
                if (rt == 0) rs0 += p[e]; else rs1 += p[e];
            }
            union { s16x8 v; unsigned u[4]; } af;
            af.u[0] = pkbf(p[0], p[1]); af.u[1] = pkbf(p[2], p[3]);
            af.u[2] = pkbf(p[4], p[5]); af.u[3] = pkbf(p[6], p[7]);
            #pragma unroll
            for (int ot = 0; ot < 4; ++ot)
                acc[rt][ot] = __builtin_amdgcn_mfma_f32_16x16x32_bf16(
                    af.v, Bf[ot], acc[rt][ot], 0, 0, 0);
        }

        __syncthreads();    // next-step DMA done; all waves done with [cur]
        xc0 = xn0; xc1 = xn1;
        cur ^= 1;
    }

    // row-sums: reduce over g-groups (j-octets), park per block-row
    rs0 += __shfl_xor(rs0, 16); rs0 += __shfl_xor(rs0, 32);
    rs1 += __shfl_xor(rs1, 16); rs1 += __shfl_xor(rs1, 32);
    if (oh == 0 && l < 16) {
        rsum[rh * 32 + l] = rs0;
        rsum[rh * 32 + 16 + l] = rs1;
    }
    __syncthreads();

    const size_t sb = (size_t)blockIdx.y * ((size_t)NROWS * FO_);
    #pragma unroll
    for (int rt = 0; rt < 2; ++rt) {
        #pragma unroll
        for (int kk = 0; kk < 4; ++kk) {
            int rloc = rh * 32 + rt * 16 + g * 4 + kk;
            int grow = bN + rblk + rloc;
            float* pp = pacc + sb + (size_t)grow * FO_ + oh * 64 + lr;
            #pragma unroll
            for (int ot = 0; ot < 4; ++ot)
                pp[ot * 16] = acc[rt][ot][kk];
            if (oh == 0 && lr == 0)
                prow[blockIdx.y * NROWS + grow] = rsum[rloc];
        }
    }
}

// ---------------- K4: combine split partials + normalize ----------------
__global__ __launch_bounds__(256) void k4_comb(
    const float* __restrict__ pacc, const float* __restrict__ prow,
    float* __restrict__ out)
{
    const int idx = blockIdx.x * 256 + threadIdx.x;      // 2,097,152
    const int grow = idx >> 7;
    float s = 0.f, rs = 0.f;
    #pragma unroll
    for (int si = 0; si < SPLIT; ++si) {
        s  += pacc[(size_t)si * ((size_t)NROWS * FO_) + idx];
        rs += prow[si * NROWS + grow];
    }
    out[idx] = s / rs;
}

extern "C" void kernel_launch(void* const* d_in, const int* in_sizes, int n_in,
                              void* d_out, int out_size, void* d_ws, size_t ws_size,
                              hipStream_t stream)
{
    const float* h  = (const float*)d_in[0];
    const int* adj  = (const int*)d_in[1];
    const float* Ww = (const float*)d_in[2];
    const float* Wb = (const float*)d_in[3];
    const float* aw = (const float*)d_in[4];
    const float* ab = (const float*)d_in[5];
    float* out = (float*)d_out;

    char* wsb = (char*)d_ws;                             // ws_size ~1 GB
    float* pacc          = (float*)wsb;                               // 32 MB
    short* WhTf          = (short*)(wsb + 33554432u);                 // 4 MB
    char* aux            = wsb + 37748736u;
    float* srcv          = (float*)(aux);                             // 64 KB
    unsigned* auxp       = (unsigned*)(aux + (64u << 10));            // 64 KB
    __hip_bfloat16* whi  = (__hip_bfloat16*)(aux + (128u << 10));     // 64 KB
    __hip_bfloat16* wlo  = (__hip_bfloat16*)(aux + (192u << 10));     // 64 KB
    unsigned* maxenc     = (unsigned*)(aux + (256u << 10));           // 16 B
    float* prow          = (float*)(aux + (320u << 10));              // 256 KB

    k0_packw<<<128, 256, 0, stream>>>(Ww, whi, wlo, maxenc);
    k1_wh<<<1024, 256, 0, stream>>>(h, whi, wlo, Wb, aw, ab, WhTf, srcv, auxp, maxenc);
    dim3 g3(NB_ * 64, SPLIT);
    k3_gat<<<g3, 256, 0, stream>>>(adj, WhTf, srcv, auxp, maxenc, pacc, prow);
    k4_comb<<<8192, 256, 0, stream>>>(pacc, prow, out);
}